// Round 1
// baseline (132.300 us; speedup 1.0000x reference)
//
#include <hip/hip_runtime.h>

#define NUM_FIELDS 10
#define EMB 64
#define ROW 128            // 2 * EMB floats per embedding row
#define WAVES_PER_BLOCK 4  // 256 threads

__global__ __launch_bounds__(256) void fm_ho_kernel(
    const int* __restrict__ x, const int* __restrict__ offsets,
    const float* __restrict__ W_emb, const float* __restrict__ W_lin,
    const float* __restrict__ bias, float* __restrict__ out, int batch)
{
    const int lane = threadIdx.x & 63;
    const int wave = threadIdx.x >> 6;
    const int b = blockIdx.x * WAVES_PER_BLOCK + wave;
    if (b >= batch) return;

    // All lanes load the same 10 indices (wave-uniform address -> L1 broadcast).
    int ids[NUM_FIELDS];
#pragma unroll
    for (int f = 0; f < NUM_FIELDS; ++f)
        ids[f] = x[b * NUM_FIELDS + f] + offsets[f];

    // Power sums per dim: first 64 dims (FM order-2), last 64 dims (ANOVA order-3).
    float s1a = 0.f, s2a = 0.f;            // p1, p2 for dims [0,64)
    float s1b = 0.f, s2b = 0.f, s3b = 0.f; // p1, p2, p3 for dims [64,128)
#pragma unroll
    for (int f = 0; f < NUM_FIELDS; ++f) {
        const float* row = W_emb + (size_t)ids[f] * ROW;
        float e1 = row[lane];        // coalesced: lane i -> consecutive floats
        float e2 = row[EMB + lane];
        s1a += e1;
        s2a = fmaf(e1, e1, s2a);
        s1b += e2;
        float e2sq = e2 * e2;
        s2b += e2sq;
        s3b = fmaf(e2sq, e2, s3b);
    }

    // e2(pairs) = 0.5*(p1^2 - p2); e3(triples) = (p1^3 - 3 p1 p2 + 2 p3)/6
    float v = 0.5f * (s1a * s1a - s2a)
            + (s1b * s1b * s1b - 3.f * s1b * s2b + 2.f * s3b) * (1.f / 6.f);

    // Linear term: lanes 0..9 each contribute one W_lin entry before reduction.
    if (lane < NUM_FIELDS) v += W_lin[ids[lane]];

    // Wave-wide butterfly reduction (64 lanes).
#pragma unroll
    for (int off = 32; off; off >>= 1)
        v += __shfl_xor(v, off, 64);

    if (lane == 0) {
        float y = v + bias[0];
        out[b] = y > 0.f ? y : 0.f;
    }
}

extern "C" void kernel_launch(void* const* d_in, const int* in_sizes, int n_in,
                              void* d_out, int out_size, void* d_ws, size_t ws_size,
                              hipStream_t stream) {
    const int*   x       = (const int*)d_in[0];
    const int*   offsets = (const int*)d_in[1];
    const float* W_emb   = (const float*)d_in[2];
    const float* W_lin   = (const float*)d_in[3];
    const float* bias    = (const float*)d_in[4];
    float*       out     = (float*)d_out;

    const int batch = in_sizes[0] / NUM_FIELDS; // 16384
    const int grid  = (batch + WAVES_PER_BLOCK - 1) / WAVES_PER_BLOCK;
    hipLaunchKernelGGL(fm_ho_kernel, dim3(grid), dim3(256), 0, stream,
                       x, offsets, W_emb, W_lin, bias, out, batch);
}